// Round 16
// baseline (1885.246 us; speedup 1.0000x reference)
//
#include <hip/hip_runtime.h>
#include <hip/hip_bf16.h>

typedef __bf16 bf16x8_v __attribute__((ext_vector_type(8)));
typedef float  f32x4_v  __attribute__((ext_vector_type(4)));

static constexpr int kH = 1024;
static constexpr int kD = 2048;   // 2H
static constexpr int kB = 64;
static constexpr int kS = 2048;
static constexpr int kM = kB * kS;  // 131072 rows of the big GEMM

__device__ __forceinline__ void load_lds16(const void* g, void* l) {
  __builtin_amdgcn_global_load_lds(
      (const __attribute__((address_space(1))) unsigned int*)g,
      (__attribute__((address_space(3))) unsigned int*)l, 16, 0, 0);
}

__device__ __forceinline__ float fast_tanh(float x) {
  float e = __expf(2.0f * x);
  return 1.0f - 2.0f * __builtin_amdgcn_rcpf(e + 1.0f);
}

// ---- W_h fp32 -> bf16 tiled (16x32 subtiles, XOR slot swizzle) -------------
// Output: [h/16][kt=0..63][64 chunks of 16B]. Chunk p: rr=p>>2, s=p&3;
// slot s holds k-chunk c = s ^ ((rr>>1)&3) (read: slot16 XOR, proven 0-conflict).
__global__ __launch_bounds__(256) void conv_tile_kernel(const float* __restrict__ in,
                                                        __bf16* __restrict__ out) {
  size_t g = (size_t)blockIdx.x * 256 + threadIdx.x;
  int p = (int)(g & 63);
  size_t tile = g >> 6;
  int kt = (int)(tile & 63);
  size_t mt16 = tile >> 6;
  int rr = p >> 2, s = p & 3;
  int c = s ^ ((rr >> 1) & 3);
  const float* src = in + (mt16 * 16 + rr) * (size_t)kD + kt * 32 + c * 8;
  float4 v0 = reinterpret_cast<const float4*>(src)[0];
  float4 v1 = reinterpret_cast<const float4*>(src)[1];
  bf16x8_v o = {(__bf16)v0.x, (__bf16)v0.y, (__bf16)v0.z, (__bf16)v0.w,
                (__bf16)v1.x, (__bf16)v1.y, (__bf16)v1.z, (__bf16)v1.w};
  reinterpret_cast<bf16x8_v*>(out)[g] = o;
}

// ------------- biasBH[b][h] = s_t[b] . W_s[h] + b_s[h] + b_h[h] -------------
__global__ __launch_bounds__(256) void prep_bias_kernel(
    const float* __restrict__ s_t, const float* __restrict__ W_s,
    const float* __restrict__ b_s, const float* __restrict__ b_h,
    float* __restrict__ biasBH) {
  int wave = blockIdx.x * 4 + (threadIdx.x >> 6);  // 65536 outputs
  int lane = threadIdx.x & 63;
  int b = wave >> 10, h = wave & 1023;
  const float4* sp = reinterpret_cast<const float4*>(s_t + (size_t)b * kD);
  const float4* wp = reinterpret_cast<const float4*>(W_s + (size_t)h * kD);
  float acc = 0.f;
  for (int i = lane; i < kD / 4; i += 64) {
    float4 a = sp[i], w = wp[i];
    acc += a.x * w.x + a.y * w.y + a.z * w.z + a.w * w.w;
  }
  for (int m = 1; m < 64; m <<= 1) acc += __shfl_xor(acc, m);
  if (lane == 0) biasBH[wave] = acc + b_s[h] + b_h[h];
}

// ---------------- big GEMM + fused tanh/v_a epilogue -> E -------------------
// BM=256, BN=128, BK=32 (64 tiles), 8 waves (4M x 2N), per-wave 64x64,
// acc[4][4]=64 regs -> 2 blocks/CU (R14-verified occupancy).
// A: reg-staged fp32->bf16 with DOUBLE register sets avP/avQ (the R15 bugfix:
//    LOADA(t+2) fills the set NOT consumed by this tile's WRITEA), ds_write
//    into 16x32-subtile XOR layout, 2 bufs. B: gload_lds pre-tiled Wtl, 3 bufs.
// Per tile: [lgkmcnt(0); barrier] -> issue GLOADB(t+2), LOADA(t+2,AVN) ->
// ds_read frags -> 16 MFMA -> WRITEA(AVC=A(t+1)) LAST. WRITEA's compiler
// wait on AVC (issued at t-1 after GLOADB(t+1), before this tile's loads)
// = effective vmcnt(5): new loads stay in flight across the next barrier.
// B(t)-arrival: tile t-1's WRITEA wait drains GLOADB(t) (issued before
// LOADA(t), in-order vmcnt); barrier(t) publishes.
__global__ __launch_bounds__(512, 4) void gemm_score_kernel(
    const float* __restrict__ h_i,      // (kM, kD) fp32
    const __bf16* __restrict__ Wtl,     // tiled bf16 W_h
    const float* __restrict__ biasBH,   // (kB, kH)
    const float* __restrict__ coverage, // (kB, kS)
    const float* __restrict__ Wc,       // (kH)
    const float* __restrict__ va,       // (kH)
    float* __restrict__ E) {            // (kB, kS), pre-zeroed
  const int bid = blockIdx.x;           // 4096 blocks
  const int xcd = bid & 7;
  const int slot = bid >> 3;
  const int nblk = slot & 7;            // 8 N-blocks, fastest within XCD
  const int n0 = nblk * 128;
  const int m0 = (xcd * 64 + (slot >> 3)) * 256;

  const int tid = threadIdx.x;
  const int lane = tid & 63;
  const int wid = tid >> 6;             // 0..7
  const int wm = wid >> 1, wn = wid & 1;

  __shared__ __align__(16) char lds[57344];  // A: 2x16K @0; B: 3x8K @32768

  f32x4_v acc[4][4];
#pragma unroll
  for (int m = 0; m < 4; ++m)
#pragma unroll
    for (int n = 0; n < 4; ++n) acc[m][n] = {0.f, 0.f, 0.f, 0.f};

  const int l15 = lane & 15;
  const int j = lane >> 4;
  const int slot16 = (j ^ ((l15 >> 1) & 3)) << 4;   // proven read swizzle

  // ---- A reg-staging geometry: wave wid owns rows wid*32..wid*32+31
  const int arow = wid * 32 + (lane >> 1);  // block-local row
  const int ah = lane & 1;                  // k-half (16 floats)
  const float* Ag = h_i + (size_t)(m0 + arow) * kD + ah * 16;
  const int ast = arow >> 4;
  const int arr = arow & 15;
  const int ax = (arr >> 1) & 3;
  const int aw0 = ast * 1024 + arr * 64 + (((2 * ah) ^ ax) << 4);
  const int aw1 = ast * 1024 + arr * 64 + (((2 * ah + 1) ^ ax) << 4);

  // ---- B staging: wave wid stages subtile wid (16 rows x 32 cols, 1 KB)
  const __bf16* Bsrc = Wtl + ((size_t)(nblk * 8 + wid) * 64) * 512 + lane * 8;

  f32x4_v avP[4], avQ[4];

#define LOADA(T, AV)                                                  \
  do {                                                                \
    const float* p_ = Ag + (size_t)(T) * 32;                          \
    AV[0] = *reinterpret_cast<const f32x4_v*>(p_);                    \
    AV[1] = *reinterpret_cast<const f32x4_v*>(p_ + 4);                \
    AV[2] = *reinterpret_cast<const f32x4_v*>(p_ + 8);                \
    AV[3] = *reinterpret_cast<const f32x4_v*>(p_ + 12);               \
  } while (0)

#define WRITEA(AV, BUF)                                               \
  do {                                                                \
    char* base_ = lds + (BUF) * 16384;                                \
    bf16x8_v o0_ = {(__bf16)AV[0][0], (__bf16)AV[0][1], (__bf16)AV[0][2], (__bf16)AV[0][3], \
                    (__bf16)AV[1][0], (__bf16)AV[1][1], (__bf16)AV[1][2], (__bf16)AV[1][3]}; \
    bf16x8_v o1_ = {(__bf16)AV[2][0], (__bf16)AV[2][1], (__bf16)AV[2][2], (__bf16)AV[2][3], \
                    (__bf16)AV[3][0], (__bf16)AV[3][1], (__bf16)AV[3][2], (__bf16)AV[3][3]}; \
    *reinterpret_cast<bf16x8_v*>(base_ + aw0) = o0_;                  \
    *reinterpret_cast<bf16x8_v*>(base_ + aw1) = o1_;                  \
  } while (0)

#define GLOADB(T)                                                     \
  load_lds16(Bsrc + (size_t)(T) * 512, lds + 32768 + ((T) % 3) * 8192 + wid * 1024)

#define TILE16(T, AVC, AVN)                                           \
  do {                                                                \
    asm volatile("s_waitcnt lgkmcnt(0)" ::: "memory");                \
    __builtin_amdgcn_s_barrier();                                     \
    __builtin_amdgcn_sched_barrier(0);                                \
    if ((T) + 2 < 64) {                                               \
      GLOADB((T) + 2);                                                \
      LOADA((T) + 2, AVN);                                            \
    }                                                                 \
    __builtin_amdgcn_sched_barrier(0);                                \
    const char* Ab_ = lds + ((T) & 1) * 16384;                        \
    const char* Bb_ = lds + 32768 + ((T) % 3) * 8192;                 \
    bf16x8_v b_[4], a_[4];                                            \
    _Pragma("unroll")                                                 \
    for (int n = 0; n < 4; ++n)                                       \
      b_[n] = *reinterpret_cast<const bf16x8_v*>(                     \
          Bb_ + (wn * 4 + n) * 1024 + l15 * 64 + slot16);             \
    _Pragma("unroll")                                                 \
    for (int mi = 0; mi < 4; ++mi)                                    \
      a_[mi] = *reinterpret_cast<const bf16x8_v*>(                    \
          Ab_ + (wm * 4 + mi) * 1024 + l15 * 64 + slot16);            \
    __builtin_amdgcn_s_setprio(1);                                    \
    _Pragma("unroll")                                                 \
    for (int mi = 0; mi < 4; ++mi)                                    \
      _Pragma("unroll")                                               \
      for (int n = 0; n < 4; ++n)                                     \
        acc[mi][n] = __builtin_amdgcn_mfma_f32_16x16x32_bf16(a_[mi], b_[n], acc[mi][n], 0, 0, 0); \
    __builtin_amdgcn_s_setprio(0);                                    \
    if ((T) + 1 < 64) WRITEA(AVC, ((T) + 1) & 1);                     \
  } while (0)

  // ---- prologue: B(0),B(1) in flight; A(0) loaded+written; A(1) -> avP.
  GLOADB(0);
  GLOADB(1);
  LOADA(0, avP);
  asm volatile("s_waitcnt vmcnt(0)" ::: "memory");
  WRITEA(avP, 0);
  LOADA(1, avP);
  // tile 0's cluster provides lgkmcnt(0)+barrier (publishes Abuf0 and B(0)).

  for (int t = 0; t < 64; t += 2) {
    TILE16(t, avP, avQ);       // consumes A(t+1)=avP, prefetches A(t+2)->avQ
    TILE16(t + 1, avQ, avP);   // consumes A(t+2)=avQ, prefetches A(t+3)->avP
  }

#undef LOADA
#undef WRITEA
#undef GLOADB
#undef TILE16

  // ---- epilogue: z = acc + bias + cov*Wc; E_partial = sum_h tanh(z)*va[h]
  const int bb = m0 >> 11;              // batch (uniform per block)
  const int colg = lane & 15;
  const int rowg = lane >> 4;           // 0..3
  float bias_v[4], wc_v[4], va_v[4];
#pragma unroll
  for (int n = 0; n < 4; ++n) {
    int h = n0 + wn * 64 + n * 16 + colg;
    bias_v[n] = biasBH[bb * kH + h];
    wc_v[n] = Wc[h];
    va_v[n] = va[h];
  }
  const int s_tile = (m0 & (kS - 1));
#pragma unroll
  for (int m = 0; m < 4; ++m) {
    int sbase = s_tile + wm * 64 + m * 16 + rowg * 4;
    float cov[4], rowsum[4];
#pragma unroll
    for (int q = 0; q < 4; ++q) {
      cov[q] = coverage[bb * kS + sbase + q];
      rowsum[q] = 0.f;
    }
#pragma unroll
    for (int n = 0; n < 4; ++n) {
#pragma unroll
      for (int q = 0; q < 4; ++q) {
        float z = acc[m][n][q] + bias_v[n] + cov[q] * wc_v[n];
        rowsum[q] += fast_tanh(z) * va_v[n];
      }
    }
#pragma unroll
    for (int q = 0; q < 4; ++q) {
      float v = rowsum[q];
      v += __shfl_xor(v, 1);
      v += __shfl_xor(v, 2);
      v += __shfl_xor(v, 4);
      v += __shfl_xor(v, 8);
      if (colg == 0) atomicAdd(&E[bb * kS + sbase + q], v);
    }
  }
}

// ---------------- softmax over S per (b); A and new_cov ---------------------
__global__ __launch_bounds__(256) void softmax_kernel(
    const float* __restrict__ E, const float* __restrict__ coverage,
    float* __restrict__ A, float* __restrict__ newcov) {
  int b = blockIdx.x;
  int tid = threadIdx.x;
  int wid = tid >> 6, lane = tid & 63;
  __shared__ float wred[4];
  float ev[8];
  float mx = -INFINITY;
#pragma unroll
  for (int i = 0; i < 8; ++i) {
    ev[i] = E[b * kS + tid + i * 256];
    mx = fmaxf(mx, ev[i]);
  }
  for (int m = 1; m < 64; m <<= 1) mx = fmaxf(mx, __shfl_xor(mx, m));
  if (lane == 0) wred[wid] = mx;
  __syncthreads();
  mx = fmaxf(fmaxf(wred[0], wred[1]), fmaxf(wred[2], wred[3]));
  __syncthreads();
  float sum = 0.f;
#pragma unroll
  for (int i = 0; i < 8; ++i) {
    ev[i] = __expf(ev[i] - mx);
    sum += ev[i];
  }
  for (int m = 1; m < 64; m <<= 1) sum += __shfl_xor(sum, m);
  if (lane == 0) wred[wid] = sum;
  __syncthreads();
  sum = wred[0] + wred[1] + wred[2] + wred[3];
  float inv = 1.f / sum;
#pragma unroll
  for (int i = 0; i < 8; ++i) {
    int s = tid + i * 256;
    float a = ev[i] * inv;
    A[b * kS + s] = a;
    newcov[b * kS + s] = coverage[b * kS + s] + a;
  }
}

// ---------------- context C[b] = sum_s A[b,s] * h_i[b,s,:] ------------------
__global__ __launch_bounds__(256) void context_kernel(
    const float* __restrict__ h_i, const float* __restrict__ A,
    float* __restrict__ C) {
  int b = blockIdx.x;
  int d = blockIdx.y * 1024 + threadIdx.x * 4;
  int s0 = blockIdx.z * 256;
  const float* hp = h_i + ((size_t)b * kS + s0) * kD + d;
  const float* ap = A + b * kS + s0;
  float4 acc = {0.f, 0.f, 0.f, 0.f};
  for (int s = 0; s < 256; ++s) {
    float a = ap[s];
    float4 v = *reinterpret_cast<const float4*>(hp + (size_t)s * kD);
    acc.x += a * v.x;
    acc.y += a * v.y;
    acc.z += a * v.z;
    acc.w += a * v.w;
  }
  atomicAdd(&C[b * kD + d + 0], acc.x);
  atomicAdd(&C[b * kD + d + 1], acc.y);
  atomicAdd(&C[b * kD + d + 2], acc.z);
  atomicAdd(&C[b * kD + d + 3], acc.w);
}

extern "C" void kernel_launch(void* const* d_in, const int* in_sizes, int n_in,
                              void* d_out, int out_size, void* d_ws, size_t ws_size,
                              hipStream_t stream) {
  const float* s_t      = (const float*)d_in[0];
  const float* h_i      = (const float*)d_in[1];
  const float* coverage = (const float*)d_in[2];
  const float* W_h      = (const float*)d_in[3];
  const float* b_h      = (const float*)d_in[4];
  const float* W_s      = (const float*)d_in[5];
  const float* b_s      = (const float*)d_in[6];
  const float* W_c      = (const float*)d_in[7];
  const float* v_a      = (const float*)d_in[8];
  // d_in[9] = b_a: softmax-shift-invariant and E is not an output -> unused.

  float* out = (float*)d_out;
  float* C      = out;                 // (kB, kD)
  float* A      = out + kB * kD;       // (kB, kS)
  float* newcov = A + kB * kS;         // (kB, kS)

  char* ws = (char*)d_ws;
  __bf16* Wtl   = (__bf16*)ws;                                // 4 MB tiled W_h
  float* biasBH = (float*)(ws + (4u << 20));                  // 256 KB
  float* E      = (float*)(ws + (4u << 20) + (256u << 10));   // 512 KB

  hipMemsetAsync(E, 0, (size_t)kB * kS * sizeof(float), stream);
  hipMemsetAsync(C, 0, (size_t)kB * kD * sizeof(float), stream);

  conv_tile_kernel<<<kH, 256, 0, stream>>>(W_h, Wtl);
  prep_bias_kernel<<<(kB * kH) / 4, 256, 0, stream>>>(s_t, W_s, b_s, b_h, biasBH);

  gemm_score_kernel<<<4096, 512, 0, stream>>>(h_i, Wtl, biasBH, coverage,
                                              W_c, v_a, E);

  softmax_kernel<<<kB, 256, 0, stream>>>(E, coverage, A, newcov);

  dim3 gc(kB, kD / 1024, kS / 256);
  context_kernel<<<gc, 256, 0, stream>>>(h_i, A, C);
}

// Round 17
// 1028.951 us; speedup vs baseline: 1.8322x; 1.8322x over previous
//
#include <hip/hip_runtime.h>
#include <hip/hip_bf16.h>

typedef __bf16 bf16x8_v __attribute__((ext_vector_type(8)));
typedef float  f32x4_v  __attribute__((ext_vector_type(4)));

static constexpr int kH = 1024;
static constexpr int kD = 2048;   // 2H
static constexpr int kB = 64;
static constexpr int kS = 2048;
static constexpr int kM = kB * kS;  // 131072 rows of the big GEMM

__device__ __forceinline__ void load_lds16(const void* g, void* l) {
  __builtin_amdgcn_global_load_lds(
      (const __attribute__((address_space(1))) unsigned int*)g,
      (__attribute__((address_space(3))) unsigned int*)l, 16, 0, 0);
}

__device__ __forceinline__ float fast_tanh(float x) {
  float e = __expf(2.0f * x);
  return 1.0f - 2.0f * __builtin_amdgcn_rcpf(e + 1.0f);
}

// ---- W_h fp32 -> bf16 tiled (16x32 subtiles, XOR slot swizzle) -------------
// Output: [h/16][kt=0..63][64 chunks of 16B]. Chunk p: rr=p>>2, s=p&3;
// slot s holds k-chunk c = s ^ ((rr>>1)&3) (read: slot16 XOR, proven 0-conflict).
__global__ __launch_bounds__(256) void conv_tile_kernel(const float* __restrict__ in,
                                                        __bf16* __restrict__ out) {
  size_t g = (size_t)blockIdx.x * 256 + threadIdx.x;
  int p = (int)(g & 63);
  size_t tile = g >> 6;
  int kt = (int)(tile & 63);
  size_t mt16 = tile >> 6;
  int rr = p >> 2, s = p & 3;
  int c = s ^ ((rr >> 1) & 3);
  const float* src = in + (mt16 * 16 + rr) * (size_t)kD + kt * 32 + c * 8;
  float4 v0 = reinterpret_cast<const float4*>(src)[0];
  float4 v1 = reinterpret_cast<const float4*>(src)[1];
  bf16x8_v o = {(__bf16)v0.x, (__bf16)v0.y, (__bf16)v0.z, (__bf16)v0.w,
                (__bf16)v1.x, (__bf16)v1.y, (__bf16)v1.z, (__bf16)v1.w};
  reinterpret_cast<bf16x8_v*>(out)[g] = o;
}

// ------------- biasBH[b][h] = s_t[b] . W_s[h] + b_s[h] + b_h[h] -------------
__global__ __launch_bounds__(256) void prep_bias_kernel(
    const float* __restrict__ s_t, const float* __restrict__ W_s,
    const float* __restrict__ b_s, const float* __restrict__ b_h,
    float* __restrict__ biasBH) {
  int wave = blockIdx.x * 4 + (threadIdx.x >> 6);  // 65536 outputs
  int lane = threadIdx.x & 63;
  int b = wave >> 10, h = wave & 1023;
  const float4* sp = reinterpret_cast<const float4*>(s_t + (size_t)b * kD);
  const float4* wp = reinterpret_cast<const float4*>(W_s + (size_t)h * kD);
  float acc = 0.f;
  for (int i = lane; i < kD / 4; i += 64) {
    float4 a = sp[i], w = wp[i];
    acc += a.x * w.x + a.y * w.y + a.z * w.z + a.w * w.w;
  }
  for (int m = 1; m < 64; m <<= 1) acc += __shfl_xor(acc, m);
  if (lane == 0) biasBH[wave] = acc + b_s[h] + b_h[h];
}

// ---------------- big GEMM + fused tanh/v_a epilogue -> E -------------------
// BM=128, BN=128, BK=32 (64 tiles), 4 waves (2M x 2N), per-wave 64x64,
// 256 threads. Per-thread schedule and footprint IDENTICAL to R14 (fits the
// 128-VGPR cap -- the R16 spill is impossible), but 4 blocks/CU:
// LDS 40 KB x 4 = 160 KB, 4 independent barrier groups cover each other's
// WRITEA drains (the R14 weakness at 2 blocks).
// A: reg-staged fp32->bf16, ds_write into 16x32-subtile XOR layout, 2 bufs.
// B: gload_lds from pre-tiled Wtl, 3 bufs.
// Per tile: [lgkm0; barrier] -> WRITEA(A(t+1)) -> issue GLOADB(t+2),
// LOADA(t+2) -> ds_read frags -> 16 MFMA.
__global__ __launch_bounds__(256, 4) void gemm_score_kernel(
    const float* __restrict__ h_i,      // (kM, kD) fp32
    const __bf16* __restrict__ Wtl,     // tiled bf16 W_h
    const float* __restrict__ biasBH,   // (kB, kH)
    const float* __restrict__ coverage, // (kB, kS)
    const float* __restrict__ Wc,       // (kH)
    const float* __restrict__ va,       // (kH)
    float* __restrict__ E) {            // (kB, kS), pre-zeroed
  const int bid = blockIdx.x;           // 8192 blocks
  const int xcd = bid & 7;
  const int slot = bid >> 3;
  const int nblk = slot & 7;            // 8 N-blocks, fastest within XCD
  const int n0 = nblk * 128;
  const int m0 = (xcd * 128 + (slot >> 3)) * 128;

  const int tid = threadIdx.x;
  const int lane = tid & 63;
  const int wid = tid >> 6;             // 0..3
  const int wm = wid >> 1, wn = wid & 1;

  __shared__ __align__(16) char lds[40960];  // A: 2x8K @0; B: 3x8K @16384

  f32x4_v acc[4][4];
#pragma unroll
  for (int m = 0; m < 4; ++m)
#pragma unroll
    for (int n = 0; n < 4; ++n) acc[m][n] = {0.f, 0.f, 0.f, 0.f};

  const int l15 = lane & 15;
  const int j = lane >> 4;
  const int slot16 = (j ^ ((l15 >> 1) & 3)) << 4;   // proven read swizzle

  // ---- A reg-staging geometry: wave wid owns rows wid*32..wid*32+31
  const int arow = wid * 32 + (lane >> 1);  // block-local row (0..127)
  const int ah = lane & 1;                  // k-half (16 floats)
  const float* Ag = h_i + (size_t)(m0 + arow) * kD + ah * 16;
  const int ast = arow >> 4;                // subtile 0..7
  const int arr = arow & 15;
  const int ax = (arr >> 1) & 3;
  const int aw0 = ast * 1024 + arr * 64 + (((2 * ah) ^ ax) << 4);
  const int aw1 = ast * 1024 + arr * 64 + (((2 * ah + 1) ^ ax) << 4);

  // ---- B staging: wave wid stages subtiles wid*2, wid*2+1 (1 KB each)
  const __bf16* Bsrc0 = Wtl + ((size_t)(nblk * 8 + wid * 2) * 64) * 512 + lane * 8;
  const __bf16* Bsrc1 = Wtl + ((size_t)(nblk * 8 + wid * 2 + 1) * 64) * 512 + lane * 8;

  f32x4_v av[4];

#define LOADA(T)                                                      \
  do {                                                                \
    const float* p_ = Ag + (size_t)(T) * 32;                          \
    av[0] = *reinterpret_cast<const f32x4_v*>(p_);                    \
    av[1] = *reinterpret_cast<const f32x4_v*>(p_ + 4);                \
    av[2] = *reinterpret_cast<const f32x4_v*>(p_ + 8);                \
    av[3] = *reinterpret_cast<const f32x4_v*>(p_ + 12);               \
  } while (0)

#define WRITEA(BUF)                                                   \
  do {                                                                \
    char* base_ = lds + (BUF) * 8192;                                 \
    bf16x8_v o0_ = {(__bf16)av[0][0], (__bf16)av[0][1], (__bf16)av[0][2], (__bf16)av[0][3], \
                    (__bf16)av[1][0], (__bf16)av[1][1], (__bf16)av[1][2], (__bf16)av[1][3]}; \
    bf16x8_v o1_ = {(__bf16)av[2][0], (__bf16)av[2][1], (__bf16)av[2][2], (__bf16)av[2][3], \
                    (__bf16)av[3][0], (__bf16)av[3][1], (__bf16)av[3][2], (__bf16)av[3][3]}; \
    *reinterpret_cast<bf16x8_v*>(base_ + aw0) = o0_;                  \
    *reinterpret_cast<bf16x8_v*>(base_ + aw1) = o1_;                  \
  } while (0)

#define GLOADB(T)                                                     \
  do {                                                                \
    char* bd_ = lds + 16384 + ((T) % 3) * 8192;                       \
    load_lds16(Bsrc0 + (size_t)(T) * 512, bd_ + (wid * 2) * 1024);    \
    load_lds16(Bsrc1 + (size_t)(T) * 512, bd_ + (wid * 2 + 1) * 1024);\
  } while (0)

#define TILE17(T)                                                     \
  do {                                                                \
    asm volatile("s_waitcnt lgkmcnt(0)" ::: "memory");                \
    __builtin_amdgcn_s_barrier();                                     \
    __builtin_amdgcn_sched_barrier(0);                                \
    if ((T) + 1 < 64) WRITEA(((T) + 1) & 1);                          \
    if ((T) + 2 < 64) {                                               \
      GLOADB((T) + 2);                                                \
      LOADA((T) + 2);                                                 \
    }                                                                 \
    __builtin_amdgcn_sched_barrier(0);                                \
    const char* Ab_ = lds + ((T) & 1) * 8192;                         \
    const char* Bb_ = lds + 16384 + ((T) % 3) * 8192;                 \
    bf16x8_v b_[4], a_[4];                                            \
    _Pragma("unroll")                                                 \
    for (int n = 0; n < 4; ++n)                                       \
      b_[n] = *reinterpret_cast<const bf16x8_v*>(                     \
          Bb_ + (wn * 4 + n) * 1024 + l15 * 64 + slot16);             \
    _Pragma("unroll")                                                 \
    for (int mi = 0; mi < 4; ++mi)                                    \
      a_[mi] = *reinterpret_cast<const bf16x8_v*>(                    \
          Ab_ + (wm * 4 + mi) * 1024 + l15 * 64 + slot16);            \
    __builtin_amdgcn_s_setprio(1);                                    \
    _Pragma("unroll")                                                 \
    for (int mi = 0; mi < 4; ++mi)                                    \
      _Pragma("unroll")                                               \
      for (int n = 0; n < 4; ++n)                                     \
        acc[mi][n] = __builtin_amdgcn_mfma_f32_16x16x32_bf16(a_[mi], b_[n], acc[mi][n], 0, 0, 0); \
    __builtin_amdgcn_s_setprio(0);                                    \
  } while (0)

  // ---- prologue: B(0),B(1),A(0) in flight; drain; A(0)->buf0; A(1) issued.
  GLOADB(0);
  GLOADB(1);
  LOADA(0);
  asm volatile("s_waitcnt vmcnt(0)" ::: "memory");
  WRITEA(0);
  LOADA(1);
  // tile 0's cluster provides lgkmcnt(0)+barrier (publishes Abuf0; B(0) done).

  for (int t = 0; t < 64; t += 2) {
    TILE17(t);
    TILE17(t + 1);
  }

#undef LOADA
#undef WRITEA
#undef GLOADB
#undef TILE17

  // ---- epilogue: z = acc + bias + cov*Wc; E_partial = sum_h tanh(z)*va[h]
  const int bb = m0 >> 11;              // batch (uniform per block)
  const int colg = lane & 15;
  const int rowg = lane >> 4;           // 0..3
  float bias_v[4], wc_v[4], va_v[4];
#pragma unroll
  for (int n = 0; n < 4; ++n) {
    int h = n0 + wn * 64 + n * 16 + colg;
    bias_v[n] = biasBH[bb * kH + h];
    wc_v[n] = Wc[h];
    va_v[n] = va[h];
  }
  const int s_tile = (m0 & (kS - 1));
#pragma unroll
  for (int m = 0; m < 4; ++m) {
    int sbase = s_tile + wm * 64 + m * 16 + rowg * 4;
    float cov[4], rowsum[4];
#pragma unroll
    for (int q = 0; q < 4; ++q) {
      cov[q] = coverage[bb * kS + sbase + q];
      rowsum[q] = 0.f;
    }
#pragma unroll
    for (int n = 0; n < 4; ++n) {
#pragma unroll
      for (int q = 0; q < 4; ++q) {
        float z = acc[m][n][q] + bias_v[n] + cov[q] * wc_v[n];
        rowsum[q] += fast_tanh(z) * va_v[n];
      }
    }
#pragma unroll
    for (int q = 0; q < 4; ++q) {
      float v = rowsum[q];
      v += __shfl_xor(v, 1);
      v += __shfl_xor(v, 2);
      v += __shfl_xor(v, 4);
      v += __shfl_xor(v, 8);
      if (colg == 0) atomicAdd(&E[bb * kS + sbase + q], v);
    }
  }
}

// ---------------- softmax over S per (b); A and new_cov ---------------------
__global__ __launch_bounds__(256) void softmax_kernel(
    const float* __restrict__ E, const float* __restrict__ coverage,
    float* __restrict__ A, float* __restrict__ newcov) {
  int b = blockIdx.x;
  int tid = threadIdx.x;
  int wid = tid >> 6, lane = tid & 63;
  __shared__ float wred[4];
  float ev[8];
  float mx = -INFINITY;
#pragma unroll
  for (int i = 0; i < 8; ++i) {
    ev[i] = E[b * kS + tid + i * 256];
    mx = fmaxf(mx, ev[i]);
  }
  for (int m = 1; m < 64; m <<= 1) mx = fmaxf(mx, __shfl_xor(mx, m));
  if (lane == 0) wred[wid] = mx;
  __syncthreads();
  mx = fmaxf(fmaxf(wred[0], wred[1]), fmaxf(wred[2], wred[3]));
  __syncthreads();
  float sum = 0.f;
#pragma unroll
  for (int i = 0; i < 8; ++i) {
    ev[i] = __expf(ev[i] - mx);
    sum += ev[i];
  }
  for (int m = 1; m < 64; m <<= 1) sum += __shfl_xor(sum, m);
  if (lane == 0) wred[wid] = sum;
  __syncthreads();
  sum = wred[0] + wred[1] + wred[2] + wred[3];
  float inv = 1.f / sum;
#pragma unroll
  for (int i = 0; i < 8; ++i) {
    int s = tid + i * 256;
    float a = ev[i] * inv;
    A[b * kS + s] = a;
    newcov[b * kS + s] = coverage[b * kS + s] + a;
  }
}

// ---------------- context C[b] = sum_s A[b,s] * h_i[b,s,:] ------------------
__global__ __launch_bounds__(256) void context_kernel(
    const float* __restrict__ h_i, const float* __restrict__ A,
    float* __restrict__ C) {
  int b = blockIdx.x;
  int d = blockIdx.y * 1024 + threadIdx.x * 4;
  int s0 = blockIdx.z * 256;
  const float* hp = h_i + ((size_t)b * kS + s0) * kD + d;
  const float* ap = A + b * kS + s0;
  float4 acc = {0.f, 0.f, 0.f, 0.f};
  for (int s = 0; s < 256; ++s) {
    float a = ap[s];
    float4 v = *reinterpret_cast<const float4*>(hp + (size_t)s * kD);
    acc.x += a * v.x;
    acc.y += a * v.y;
    acc.z += a * v.z;
    acc.w += a * v.w;
  }
  atomicAdd(&C[b * kD + d + 0], acc.x);
  atomicAdd(&C[b * kD + d + 1], acc.y);
  atomicAdd(&C[b * kD + d + 2], acc.z);
  atomicAdd(&C[b * kD + d + 3], acc.w);
}

extern "C" void kernel_launch(void* const* d_in, const int* in_sizes, int n_in,
                              void* d_out, int out_size, void* d_ws, size_t ws_size,
                              hipStream_t stream) {
  const float* s_t      = (const float*)d_in[0];
  const float* h_i      = (const float*)d_in[1];
  const float* coverage = (const float*)d_in[2];
  const float* W_h      = (const float*)d_in[3];
  const float* b_h      = (const float*)d_in[4];
  const float* W_s      = (const float*)d_in[5];
  const float* b_s      = (const float*)d_in[6];
  const float* W_c      = (const float*)d_in[7];
  const float* v_a      = (const float*)d_in[8];
  // d_in[9] = b_a: softmax-shift-invariant and E is not an output -> unused.

  float* out = (float*)d_out;
  float* C      = out;                 // (kB, kD)
  float* A      = out + kB * kD;       // (kB, kS)
  float* newcov = A + kB * kS;         // (kB, kS)

  char* ws = (char*)d_ws;
  __bf16* Wtl   = (__bf16*)ws;                                // 4 MB tiled W_h
  float* biasBH = (float*)(ws + (4u << 20));                  // 256 KB
  float* E      = (float*)(ws + (4u << 20) + (256u << 10));   // 512 KB

  hipMemsetAsync(E, 0, (size_t)kB * kS * sizeof(float), stream);
  hipMemsetAsync(C, 0, (size_t)kB * kD * sizeof(float), stream);

  conv_tile_kernel<<<kH, 256, 0, stream>>>(W_h, Wtl);
  prep_bias_kernel<<<(kB * kH) / 4, 256, 0, stream>>>(s_t, W_s, b_s, b_h, biasBH);

  gemm_score_kernel<<<8192, 256, 0, stream>>>(h_i, Wtl, biasBH, coverage,
                                              W_c, v_a, E);

  softmax_kernel<<<kB, 256, 0, stream>>>(E, coverage, A, newcov);

  dim3 gc(kB, kD / 1024, kS / 256);
  context_kernel<<<gc, 256, 0, stream>>>(h_i, A, C);
}

// Round 18
// 851.205 us; speedup vs baseline: 2.2148x; 1.2088x over previous
//
#include <hip/hip_runtime.h>
#include <hip/hip_bf16.h>

typedef __bf16 bf16x8_v __attribute__((ext_vector_type(8)));
typedef float  f32x4_v  __attribute__((ext_vector_type(4)));

static constexpr int kH = 1024;
static constexpr int kD = 2048;   // 2H
static constexpr int kB = 64;
static constexpr int kS = 2048;
static constexpr int kM = kB * kS;  // 131072 rows of the big GEMM

__device__ __forceinline__ void load_lds16(const void* g, void* l) {
  __builtin_amdgcn_global_load_lds(
      (const __attribute__((address_space(1))) unsigned int*)g,
      (__attribute__((address_space(3))) unsigned int*)l, 16, 0, 0);
}

__device__ __forceinline__ float fast_tanh(float x) {
  float e = __expf(2.0f * x);
  return 1.0f - 2.0f * __builtin_amdgcn_rcpf(e + 1.0f);
}

// ---- W_h fp32 -> bf16 tiled (16x32 subtiles, XOR slot swizzle) -------------
// Output: [h/16][kt=0..63][64 chunks of 16B]. Chunk p: rr=p>>2, s=p&3;
// slot s holds k-chunk c = s ^ ((rr>>1)&3)  (read side: slot16 XOR, 0-conflict).
__global__ __launch_bounds__(256) void conv_tile_kernel(const float* __restrict__ in,
                                                        __bf16* __restrict__ out) {
  size_t g = (size_t)blockIdx.x * 256 + threadIdx.x;
  int p = (int)(g & 63);
  size_t tile = g >> 6;
  int kt = (int)(tile & 63);
  size_t mt16 = tile >> 6;
  int rr = p >> 2, s = p & 3;
  int c = s ^ ((rr >> 1) & 3);
  const float* src = in + (mt16 * 16 + rr) * (size_t)kD + kt * 32 + c * 8;
  float4 v0 = reinterpret_cast<const float4*>(src)[0];
  float4 v1 = reinterpret_cast<const float4*>(src)[1];
  bf16x8_v o = {(__bf16)v0.x, (__bf16)v0.y, (__bf16)v0.z, (__bf16)v0.w,
                (__bf16)v1.x, (__bf16)v1.y, (__bf16)v1.z, (__bf16)v1.w};
  reinterpret_cast<bf16x8_v*>(out)[g] = o;
}

// ------------- biasBH[b][h] = s_t[b] . W_s[h] + b_s[h] + b_h[h] -------------
__global__ __launch_bounds__(256) void prep_bias_kernel(
    const float* __restrict__ s_t, const float* __restrict__ W_s,
    const float* __restrict__ b_s, const float* __restrict__ b_h,
    float* __restrict__ biasBH) {
  int wave = blockIdx.x * 4 + (threadIdx.x >> 6);  // 65536 outputs
  int lane = threadIdx.x & 63;
  int b = wave >> 10, h = wave & 1023;
  const float4* sp = reinterpret_cast<const float4*>(s_t + (size_t)b * kD);
  const float4* wp = reinterpret_cast<const float4*>(W_s + (size_t)h * kD);
  float acc = 0.f;
  for (int i = lane; i < kD / 4; i += 64) {
    float4 a = sp[i], w = wp[i];
    acc += a.x * w.x + a.y * w.y + a.z * w.z + a.w * w.w;
  }
  for (int m = 1; m < 64; m <<= 1) acc += __shfl_xor(acc, m);
  if (lane == 0) biasBH[wave] = acc + b_s[h] + b_h[h];
}

// ---------------- big GEMM + fused tanh/v_a epilogue -> E -------------------
// BM=256, BN=256, BK=32 (64 K-tiles), 8 waves (2M x 4N), per-wave 128x64.
// A: raw fp32 h_i staged via global_load_lds with per-lane XOR-swizzled
//    SOURCE addresses; fp32->bf16 AFTER ds_read.
// B: pre-tiled bf16 W_h (conv_tile_kernel), slot16 XOR reads.
// 3-deep LDS (3 x 48 KB = 144 KB, 1 block/CU), stage 2 tiles ahead,
// ONE barrier + ONE counted vmcnt(6) per K-tile (never drained mid-loop).
__global__ __launch_bounds__(512, 2) void gemm_score_kernel(
    const float* __restrict__ h_i,      // (kM, kD) fp32
    const __bf16* __restrict__ Wtl,     // tiled bf16 W_h
    const float* __restrict__ biasBH,   // (kB, kH)
    const float* __restrict__ coverage, // (kB, kS)
    const float* __restrict__ Wc,       // (kH)
    const float* __restrict__ va,       // (kH)
    float* __restrict__ E) {            // (kB, kS), pre-zeroed
  const int bid = blockIdx.x;           // 2048 blocks
  const int xcd = bid & 7;
  const int slot = bid >> 3;
  const int n0 = (slot & 3) * 256;      // 4 N-tiles, fastest within XCD
  const int m0 = (xcd * 64 + (slot >> 2)) * 256;

  const int tid = threadIdx.x;
  const int lane = tid & 63;
  const int wid = tid >> 6;             // 0..7
  const int wm = wid >> 2, wn = wid & 3;

  __shared__ char lds[3 * 49152];       // per buf: A fp32 32K + B bf16 16K

  f32x4_v acc[8][4];
#pragma unroll
  for (int m = 0; m < 8; ++m)
#pragma unroll
    for (int n = 0; n < 4; ++n) acc[m][n] = {0.f, 0.f, 0.f, 0.f};

  const int l15 = lane & 15;
  const int j = lane >> 4;              // k-group 0..3
  const int s7 = lane & 7;
  const int aco0 = ((2 * j) ^ s7) << 4; // A chunk byte offsets (XOR family)
  const int aco1 = aco0 ^ 16;
  const int slot16 = ((j ^ ((l15 >> 1) & 3)) << 4);  // B read swizzle

  // ---- staging geometry (wave-uniform LDS dest, per-lane global src)
  const int awr = lane >> 3;            // row within window 0..7
  const int awc = (lane & 7) ^ awr;     // src chunk for this lane (inverse XOR)
  const float* Asrc[4];
  char* Adst[4];
#pragma unroll
  for (int w = 0; w < 4; ++w) {
    int win = wid * 4 + w;
    Asrc[w] = h_i + (size_t)(m0 + win * 8 + awr) * kD + awc * 4;
    Adst[w] = (char*)lds + win * 1024;
  }
  const int nt16b = (slot & 3) * 16;
  const __bf16* Bsrc[2];
  char* Bdst[2];
#pragma unroll
  for (int s = 0; s < 2; ++s) {
    Bsrc[s] = Wtl + ((size_t)(nt16b + wid * 2 + s) * 64) * 512 + lane * 8;
    Bdst[s] = (char*)lds + 32768 + (wid * 2 + s) * 1024;
  }

#define STAGE(T)                                                       \
  do {                                                                 \
    int bo = ((T) % 3) * 49152;                                        \
    load_lds16(Asrc[0] + (T) * 32, Adst[0] + bo);                      \
    load_lds16(Asrc[1] + (T) * 32, Adst[1] + bo);                      \
    load_lds16(Asrc[2] + (T) * 32, Adst[2] + bo);                      \
    load_lds16(Asrc[3] + (T) * 32, Adst[3] + bo);                      \
    load_lds16(Bsrc[0] + (size_t)(T) * 512, Bdst[0] + bo);             \
    load_lds16(Bsrc[1] + (size_t)(T) * 512, Bdst[1] + bo);             \
  } while (0)

#define RD_A(AF, I, AB)                                                          \
  do {                                                                           \
    int row = wm * 128 + (I) * 16 + l15;                                         \
    const char* base = (AB) + row * 128;                                         \
    f32x4_v lo = *reinterpret_cast<const f32x4_v*>(base + aco0);                 \
    f32x4_v hi = *reinterpret_cast<const f32x4_v*>(base + aco1);                 \
    AF = bf16x8_v{(__bf16)lo[0], (__bf16)lo[1], (__bf16)lo[2], (__bf16)lo[3],    \
                  (__bf16)hi[0], (__bf16)hi[1], (__bf16)hi[2], (__bf16)hi[3]};   \
  } while (0)

#define TILE(T, DO_STAGE, WAITN)                                       \
  do {                                                                 \
    asm volatile("s_waitcnt vmcnt(" #WAITN ")" ::: "memory");          \
    __builtin_amdgcn_s_barrier();                                      \
    asm volatile("" ::: "memory");                                     \
    if (DO_STAGE) STAGE((T) + 2);                                      \
    const char* Ab = (const char*)lds + ((T) % 3) * 49152;             \
    const char* Bb = Ab + 32768;                                       \
    bf16x8_v b[4];                                                     \
    _Pragma("unroll")                                                  \
    for (int n = 0; n < 4; ++n) {                                      \
      int row = wn * 64 + n * 16 + l15;                                \
      b[n] = *reinterpret_cast<const bf16x8_v*>(                       \
          Bb + (row >> 4) * 1024 + (row & 15) * 64 + slot16);          \
    }                                                                  \
    bf16x8_v a0, a1, a2, a3;                                           \
    RD_A(a0, 0, Ab); RD_A(a1, 1, Ab); RD_A(a2, 2, Ab); RD_A(a3, 3, Ab);\
    __builtin_amdgcn_s_setprio(1);                                     \
    _Pragma("unroll")                                                  \
    for (int n = 0; n < 4; ++n) {                                      \
      acc[0][n] = __builtin_amdgcn_mfma_f32_16x16x32_bf16(a0, b[n], acc[0][n], 0, 0, 0); \
      acc[1][n] = __builtin_amdgcn_mfma_f32_16x16x32_bf16(a1, b[n], acc[1][n], 0, 0, 0); \
      acc[2][n] = __builtin_amdgcn_mfma_f32_16x16x32_bf16(a2, b[n], acc[2][n], 0, 0, 0); \
      acc[3][n] = __builtin_amdgcn_mfma_f32_16x16x32_bf16(a3, b[n], acc[3][n], 0, 0, 0); \
    }                                                                  \
    __builtin_amdgcn_s_setprio(0);                                     \
    RD_A(a0, 4, Ab); RD_A(a1, 5, Ab); RD_A(a2, 6, Ab); RD_A(a3, 7, Ab);\
    __builtin_amdgcn_s_setprio(1);                                     \
    _Pragma("unroll")                                                  \
    for (int n = 0; n < 4; ++n) {                                      \
      acc[4][n] = __builtin_amdgcn_mfma_f32_16x16x32_bf16(a0, b[n], acc[4][n], 0, 0, 0); \
      acc[5][n] = __builtin_amdgcn_mfma_f32_16x16x32_bf16(a1, b[n], acc[5][n], 0, 0, 0); \
      acc[6][n] = __builtin_amdgcn_mfma_f32_16x16x32_bf16(a2, b[n], acc[6][n], 0, 0, 0); \
      acc[7][n] = __builtin_amdgcn_mfma_f32_16x16x32_bf16(a3, b[n], acc[7][n], 0, 0, 0); \
    }                                                                  \
    __builtin_amdgcn_s_setprio(0);                                     \
  } while (0)

  // prologue: stage tiles 0,1
  STAGE(0);
  STAGE(1);

  for (int t = 0; t < 60; t += 3) {
    TILE(t, 1, 6);
    TILE(t + 1, 1, 6);
    TILE(t + 2, 1, 6);
  }
  TILE(60, 1, 6);   // stages 62
  TILE(61, 1, 6);   // stages 63
  TILE(62, 0, 6);
  TILE(63, 0, 0);

#undef STAGE
#undef RD_A
#undef TILE

  // ---- epilogue: z = acc + bias + cov*Wc; E_partial = sum_h tanh(z)*va[h]
  const int bb = m0 >> 11;              // batch (uniform per block)
  const int colg = lane & 15;
  const int rowg = lane >> 4;           // 0..3
  float bias_v[4], wc_v[4], va_v[4];
#pragma unroll
  for (int n = 0; n < 4; ++n) {
    int h = n0 + wn * 64 + n * 16 + colg;
    bias_v[n] = biasBH[bb * kH + h];
    wc_v[n] = Wc[h];
    va_v[n] = va[h];
  }
  const int s_tile = (m0 & (kS - 1));
#pragma unroll
  for (int m = 0; m < 8; ++m) {
    int sbase = s_tile + wm * 128 + m * 16 + rowg * 4;
    float cov[4], rowsum[4];
#pragma unroll
    for (int q = 0; q < 4; ++q) {
      cov[q] = coverage[bb * kS + sbase + q];
      rowsum[q] = 0.f;
    }
#pragma unroll
    for (int n = 0; n < 4; ++n) {
#pragma unroll
      for (int q = 0; q < 4; ++q) {
        float z = acc[m][n][q] + bias_v[n] + cov[q] * wc_v[n];
        rowsum[q] += fast_tanh(z) * va_v[n];
      }
    }
#pragma unroll
    for (int q = 0; q < 4; ++q) {
      float v = rowsum[q];
      v += __shfl_xor(v, 1);
      v += __shfl_xor(v, 2);
      v += __shfl_xor(v, 4);
      v += __shfl_xor(v, 8);
      if (colg == 0) atomicAdd(&E[bb * kS + sbase + q], v);
    }
  }
}

// ---------------- softmax over S per (b); A and new_cov ---------------------
__global__ __launch_bounds__(256) void softmax_kernel(
    const float* __restrict__ E, const float* __restrict__ coverage,
    float* __restrict__ A, float* __restrict__ newcov) {
  int b = blockIdx.x;
  int tid = threadIdx.x;
  int wid = tid >> 6, lane = tid & 63;
  __shared__ float wred[4];
  float ev[8];
  float mx = -INFINITY;
#pragma unroll
  for (int i = 0; i < 8; ++i) {
    ev[i] = E[b * kS + tid + i * 256];
    mx = fmaxf(mx, ev[i]);
  }
  for (int m = 1; m < 64; m <<= 1) mx = fmaxf(mx, __shfl_xor(mx, m));
  if (lane == 0) wred[wid] = mx;
  __syncthreads();
  mx = fmaxf(fmaxf(wred[0], wred[1]), fmaxf(wred[2], wred[3]));
  __syncthreads();
  float sum = 0.f;
#pragma unroll
  for (int i = 0; i < 8; ++i) {
    ev[i] = __expf(ev[i] - mx);
    sum += ev[i];
  }
  for (int m = 1; m < 64; m <<= 1) sum += __shfl_xor(sum, m);
  if (lane == 0) wred[wid] = sum;
  __syncthreads();
  sum = wred[0] + wred[1] + wred[2] + wred[3];
  float inv = 1.f / sum;
#pragma unroll
  for (int i = 0; i < 8; ++i) {
    int s = tid + i * 256;
    float a = ev[i] * inv;
    A[b * kS + s] = a;
    newcov[b * kS + s] = coverage[b * kS + s] + a;
  }
}

// ---------------- context C[b] = sum_s A[b,s] * h_i[b,s,:] ------------------
__global__ __launch_bounds__(256) void context_kernel(
    const float* __restrict__ h_i, const float* __restrict__ A,
    float* __restrict__ C) {
  int b = blockIdx.x;
  int d = blockIdx.y * 1024 + threadIdx.x * 4;
  int s0 = blockIdx.z * 256;
  const float* hp = h_i + ((size_t)b * kS + s0) * kD + d;
  const float* ap = A + b * kS + s0;
  float4 acc = {0.f, 0.f, 0.f, 0.f};
  for (int s = 0; s < 256; ++s) {
    float a = ap[s];
    float4 v = *reinterpret_cast<const float4*>(hp + (size_t)s * kD);
    acc.x += a * v.x;
    acc.y += a * v.y;
    acc.z += a * v.z;
    acc.w += a * v.w;
  }
  atomicAdd(&C[b * kD + d + 0], acc.x);
  atomicAdd(&C[b * kD + d + 1], acc.y);
  atomicAdd(&C[b * kD + d + 2], acc.z);
  atomicAdd(&C[b * kD + d + 3], acc.w);
}

extern "C" void kernel_launch(void* const* d_in, const int* in_sizes, int n_in,
                              void* d_out, int out_size, void* d_ws, size_t ws_size,
                              hipStream_t stream) {
  const float* s_t      = (const float*)d_in[0];
  const float* h_i      = (const float*)d_in[1];
  const float* coverage = (const float*)d_in[2];
  const float* W_h      = (const float*)d_in[3];
  const float* b_h      = (const float*)d_in[4];
  const float* W_s      = (const float*)d_in[5];
  const float* b_s      = (const float*)d_in[6];
  const float* W_c      = (const float*)d_in[7];
  const float* v_a      = (const float*)d_in[8];
  // d_in[9] = b_a: softmax-shift-invariant and E is not an output -> unused.

  float* out = (float*)d_out;
  float* C      = out;                 // (kB, kD)
  float* A      = out + kB * kD;       // (kB, kS)
  float* newcov = A + kB * kS;         // (kB, kS)

  char* ws = (char*)d_ws;
  __bf16* Wtl   = (__bf16*)ws;                                // 4 MB tiled W_h
  float* biasBH = (float*)(ws + (4u << 20));                  // 256 KB
  float* E      = (float*)(ws + (4u << 20) + (256u << 10));   // 512 KB

  hipMemsetAsync(E, 0, (size_t)kB * kS * sizeof(float), stream);
  hipMemsetAsync(C, 0, (size_t)kB * kD * sizeof(float), stream);

  conv_tile_kernel<<<kH, 256, 0, stream>>>(W_h, Wtl);
  prep_bias_kernel<<<(kB * kH) / 4, 256, 0, stream>>>(s_t, W_s, b_s, b_h, biasBH);

  gemm_score_kernel<<<2048, 512, 0, stream>>>(h_i, Wtl, biasBH, coverage,
                                              W_c, v_a, E);

  softmax_kernel<<<kB, 256, 0, stream>>>(E, coverage, A, newcov);

  dim3 gc(kB, kD / 1024, kS / 256);
  context_kernel<<<gc, 256, 0, stream>>>(h_i, A, C);
}